// Round 2
// baseline (786.844 us; speedup 1.0000x reference)
//
#include <hip/hip_runtime.h>
#include <hip/hip_bf16.h>
#include <stdint.h>

// ---------------- problem constants ----------------
#define E_ 8
#define C_ 1024
#define H_ 2752
#define NTOK 8192            // B*T = 4*2048
#define CAP_ROWS 18432       // 16384 assignments + 8*256 pad, 256-aligned
#define ROUTED_MB 72         // CAP_ROWS/256
#define SHARED_MB 32         // NTOK/256
#define SHARED_HBASE 18432
#define HROWS 26624          // CAP_ROWS + NTOK

typedef unsigned short u16;
typedef __attribute__((ext_vector_type(8))) short bf16x8;   // 8 bf16 in 4 VGPRs
typedef __attribute__((ext_vector_type(4))) float f32x4;

// ---------------- ws layout (bytes) ----------------
static constexpr size_t SZ_XB    = (size_t)NTOK * C_ * 2;
static constexpr size_t SZ_WT    = (size_t)E_ * H_ * C_ * 2;
static constexpr size_t SZ_SWT   = (size_t)H_ * C_ * 2;
static constexpr size_t SZ_H     = (size_t)HROWS * H_ * 2;

static constexpr size_t OFF_XB   = 0;
static constexpr size_t OFF_W1T  = OFF_XB   + SZ_XB;
static constexpr size_t OFF_W3T  = OFF_W1T  + SZ_WT;
static constexpr size_t OFF_W2T  = OFF_W3T  + SZ_WT;
static constexpr size_t OFF_SW1T = OFF_W2T  + SZ_WT;
static constexpr size_t OFF_SW3T = OFF_SW1T + SZ_SWT;
static constexpr size_t OFF_SW2T = OFF_SW3T + SZ_SWT;
static constexpr size_t OFF_H    = OFF_SW2T + SZ_SWT;
static constexpr size_t OFF_ZP   = OFF_H    + SZ_H;                 // 16KB zero page
static constexpr size_t OFF_RIDX = OFF_ZP   + 16384;                // int[NTOK*2]
static constexpr size_t OFF_RW   = OFF_RIDX + (size_t)NTOK*2*4;     // float[NTOK*2]
static constexpr size_t OFF_OFFS = OFF_RW   + (size_t)NTOK*2*4;     // int[16]
static constexpr size_t OFF_PTOK = OFF_OFFS + 64;                   // int[CAP_ROWS]
static constexpr size_t OFF_PW   = OFF_PTOK + (size_t)CAP_ROWS*4;   // float[CAP_ROWS]
static constexpr size_t WS_NEED  = OFF_PW   + (size_t)CAP_ROWS*4;

// ---------------- helpers ----------------
__device__ __forceinline__ u16 f2bf(float f) {
  union { float f; uint32_t u; } v; v.f = f;
  uint32_t r = v.u + 0x7FFFu + ((v.u >> 16) & 1u);   // RNE
  return (u16)(r >> 16);
}

// async global->LDS, 16B per lane; LDS base wave-uniform, lane offset automatic.
__device__ __forceinline__ void gld16(const void* g, void* l) {
  uint32_t lo = (uint32_t)(uintptr_t)l;
  lo = __builtin_amdgcn_readfirstlane(lo);
  __builtin_amdgcn_global_load_lds(
      (const __attribute__((address_space(1))) void*)g,
      (__attribute__((address_space(3))) void*)(uintptr_t)lo, 16, 0, 0);
}

#define MFMA16(A,B,C) __builtin_amdgcn_mfma_f32_16x16x32_bf16((A),(B),(C),0,0,0)
#define BARX() do { asm volatile("" ::: "memory"); __builtin_amdgcn_s_barrier(); \
                    asm volatile("" ::: "memory"); } while (0)
#define VMC(N) asm volatile("s_waitcnt vmcnt(" #N ")" ::: "memory")

// ---------------- gating: fp32 scores, top-2, plus x->bf16 ----------------
__global__ __launch_bounds__(256) void gate_kernel(
    const float* __restrict__ x, const float* __restrict__ gw,
    const float* __restrict__ bias, u16* __restrict__ xb,
    int* __restrict__ ridx, float* __restrict__ rw)
{
  const int n = blockIdx.x, t = threadIdx.x;
  const float4 v = *(const float4*)(x + (size_t)n * C_ + t * 4);
  union { u16 u[4]; uint2 d; } pk;
  pk.u[0] = f2bf(v.x); pk.u[1] = f2bf(v.y); pk.u[2] = f2bf(v.z); pk.u[3] = f2bf(v.w);
  *(uint2*)(xb + (size_t)n * C_ + t * 4) = pk.d;

  float p[E_];
#pragma unroll
  for (int e = 0; e < E_; ++e) {
    const float4 g = *(const float4*)(gw + (size_t)e * C_ + t * 4);
    p[e] = v.x * g.x + v.y * g.y + v.z * g.z + v.w * g.w;
  }
#pragma unroll
  for (int e = 0; e < E_; ++e)
    for (int off = 32; off > 0; off >>= 1) p[e] += __shfl_down(p[e], off);

  __shared__ float red[4][E_];
  const int wv = t >> 6;
  if ((t & 63) == 0) {
#pragma unroll
    for (int e = 0; e < E_; ++e) red[wv][e] = p[e];
  }
  __syncthreads();
  if (t == 0) {
    float sc[E_], rt[E_];
#pragma unroll
    for (int e = 0; e < E_; ++e) {
      const float d = red[0][e] + red[1][e] + red[2][e] + red[3][e];
      const float s = 1.f / (1.f + expf(-d));
      sc[e] = s; rt[e] = s + bias[e];
    }
    int i0 = 0; float b0 = rt[0];
#pragma unroll
    for (int e = 1; e < E_; ++e) if (rt[e] > b0) { b0 = rt[e]; i0 = e; }
    int i1 = -1; float b1 = -1e30f;
#pragma unroll
    for (int e = 0; e < E_; ++e) if (e != i0 && rt[e] > b1) { b1 = rt[e]; i1 = e; }
    const float s0 = sc[i0], s1 = sc[i1];
    const float inv = 1.f / (s0 + s1 + 1e-8f);
    ridx[2 * n] = i0; ridx[2 * n + 1] = i1;
    rw[2 * n] = s0 * inv; rw[2 * n + 1] = s1 * inv;
  }
}

// ---------------- weight transpose + fp32->bf16 ----------------
__global__ __launch_bounds__(256) void transpose_cs_kernel(
    const float* __restrict__ w1, const float* __restrict__ w3,
    const float* __restrict__ sw1, const float* __restrict__ sw3,
    u16* __restrict__ w1t, u16* __restrict__ w3t,
    u16* __restrict__ sw1t, u16* __restrict__ sw3t)
{
  const int z = blockIdx.z;
  const float* src; u16* dst;
  if      (z < 8)  { src = w1 + (size_t)z * C_ * H_;       dst = w1t + (size_t)z * H_ * C_; }
  else if (z < 16) { src = w3 + (size_t)(z - 8) * C_ * H_; dst = w3t + (size_t)(z - 8) * H_ * C_; }
  else if (z == 16){ src = sw1; dst = sw1t; }
  else             { src = sw3; dst = sw3t; }
  __shared__ float tile[32][33];
  const int tx = threadIdx.x, ty = threadIdx.y;
  const int s0 = blockIdx.x * 32;   // H dim
  const int r0 = blockIdx.y * 32;   // C dim
#pragma unroll
  for (int i = 0; i < 4; ++i)
    tile[ty + 8 * i][tx] = src[(size_t)(r0 + ty + 8 * i) * H_ + s0 + tx];
  __syncthreads();
#pragma unroll
  for (int i = 0; i < 4; ++i)
    dst[(size_t)(s0 + ty + 8 * i) * C_ + r0 + tx] = f2bf(tile[tx][ty + 8 * i]);
}

__global__ __launch_bounds__(256) void transpose_sc_kernel(
    const float* __restrict__ w2, const float* __restrict__ sw2,
    u16* __restrict__ w2t, u16* __restrict__ sw2t)
{
  const int z = blockIdx.z;
  const float* src; u16* dst;
  if (z < 8) { src = w2 + (size_t)z * H_ * C_; dst = w2t + (size_t)z * C_ * H_; }
  else       { src = sw2; dst = sw2t; }
  __shared__ float tile[32][33];
  const int tx = threadIdx.x, ty = threadIdx.y;
  const int s0 = blockIdx.x * 32;   // C dim
  const int r0 = blockIdx.y * 32;   // H dim
#pragma unroll
  for (int i = 0; i < 4; ++i)
    tile[ty + 8 * i][tx] = src[(size_t)(r0 + ty + 8 * i) * C_ + s0 + tx];
  __syncthreads();
#pragma unroll
  for (int i = 0; i < 4; ++i)
    dst[(size_t)(s0 + ty + 8 * i) * H_ + r0 + tx] = f2bf(tile[tx][ty + 8 * i]);
}

// ---------------- deterministic routing scan/scatter (single block) ----------------
__global__ __launch_bounds__(256) void route_scan_kernel(
    const int* __restrict__ ridx, const float* __restrict__ rw,
    int* __restrict__ offsets, int* __restrict__ perm_tok, float* __restrict__ perm_w)
{
  __shared__ int cnt[256][E_];
  __shared__ int pref[E_][257];
  __shared__ int offs[E_ + 1];
  __shared__ int totals[E_];
  const int t = threadIdx.x;
#pragma unroll
  for (int e = 0; e < E_; ++e) cnt[t][e] = 0;
  for (int j = 0; j < 64; ++j) { const int e = ridx[t * 64 + j]; cnt[t][e]++; }
  __syncthreads();
  if (t < E_) {
    int run = 0;
    for (int i = 0; i < 256; ++i) { pref[t][i] = run; run += cnt[i][t]; }
    totals[t] = run; pref[t][256] = run;
  }
  __syncthreads();
  if (t == 0) {
    int o = 0;
    for (int e = 0; e < E_; ++e) { offs[e] = o; o += (totals[e] + 255) & ~255; }
    offs[E_] = o;
    for (int i = 0; i <= E_; ++i) offsets[i] = offs[i];
  }
  __syncthreads();
#pragma unroll
  for (int e = 0; e < E_; ++e) cnt[t][e] = offs[e] + pref[e][t];
  for (int j = 0; j < 64; ++j) {
    const int a = t * 64 + j;
    const int e = ridx[a];
    const int p = cnt[t][e]++;
    perm_tok[p] = a >> 1;
    perm_w[p] = rw[a];
  }
  __syncthreads();
  for (int e = 0; e < E_; ++e) {
    for (int p = offs[e] + totals[e] + t; p < offs[e + 1]; p += 256) {
      perm_tok[p] = 0; perm_w[p] = 0.f;     // pads: valid dummy row, zero weight
    }
  }
}

// =====================================================================
// GEMM1 (8-phase): h[row,:] = silu(x@W1) * (x@W3)  -> bf16
// BM=256, BN=128, BK=64, 8 waves (2Mx4N), per-wave 128x32 per B-matrix.
// K = C = 1024 -> 16 K-tiles -> 8 iters of 2.
// LDS: A[2buf][2kh][256 rows][64B] = 64KB ; B1,B3: [2buf][2kh][128][64B] = 32KB each.
// =====================================================================
__global__ __launch_bounds__(512, 2) void gemm1_8p(
    const u16* __restrict__ xb, const u16* __restrict__ w1t_all,
    const u16* __restrict__ w3t_all, const u16* __restrict__ sw1t,
    const u16* __restrict__ sw3t, u16* __restrict__ hbuf,
    const int* __restrict__ offsets, const int* __restrict__ ptok)
{
  __shared__ char lds[131072];
  const int t = threadIdx.x;
  const int bx = blockIdx.x;
  const int n0 = blockIdx.y * 128;

  const u16 *b1w, *b3w; int row0; size_t hr0; int gather;
  if (bx < ROUTED_MB) {
    row0 = bx * 256;
    if (row0 >= offsets[8]) return;
    int e = 0;
#pragma unroll
    for (int i = 0; i < 7; ++i) if (row0 >= offsets[i + 1]) e = i + 1;
    b1w = w1t_all + (size_t)e * (H_ * C_);
    b3w = w3t_all + (size_t)e * (H_ * C_);
    hr0 = (size_t)row0; gather = 1;
  } else {
    row0 = (bx - ROUTED_MB) * 256;
    b1w = sw1t; b3w = sw3t; hr0 = (size_t)SHARED_HBASE + row0; gather = 0;
  }

  // staging sources: thread t covers LDS bytes t*16 of each 8KB issue
  const int sr = t >> 2, sc = (t & 3) << 4;
  const int ta0 = gather ? ptok[row0 + sr]       : (row0 + sr);
  const int ta1 = gather ? ptok[row0 + 128 + sr] : (row0 + 128 + sr);
  const char* aS0 = (const char*)xb + (size_t)ta0 * 2048 + sc;
  const char* aS1 = (const char*)xb + (size_t)ta1 * 2048 + sc;
  int nb = n0 + sr; if (nb > H_ - 1) nb = H_ - 1;     // N tail clamp
  const char* b1S = (const char*)b1w + (size_t)nb * 2048 + sc;
  const char* b3S = (const char*)b3w + (size_t)nb * 2048 + sc;
  const int wb = (t >> 6) << 10;
  char* ldsp = (char*)lds;

#define ARG(kt,kh)  ((((kt)&1)*2+(kh))*16384)
#define B1RG(kt,kh) (65536 + ((((kt)&1)*2+(kh))*8192))
#define B3RG(kt,kh) (98304 + ((((kt)&1)*2+(kh))*8192))
#define SA(kt,kh) do { const int go=(kt)*128+(kh)*64; \
  gld16(aS0+go, ldsp+ARG(kt,kh)+wb); gld16(aS1+go, ldsp+ARG(kt,kh)+8192+wb); } while(0)
#define SB(kt,kh) do { const int go=(kt)*128+(kh)*64; \
  gld16(b1S+go, ldsp+B1RG(kt,kh)+wb); gld16(b3S+go, ldsp+B3RG(kt,kh)+wb); } while(0)

  const int lane = t & 63, l15 = lane & 15, lhi = lane >> 4;
  const int wv = t >> 6, wm = wv >> 2, wn = wv & 3;
  int aoff[8], boff[2];
#pragma unroll
  for (int mf = 0; mf < 8; ++mf) aoff[mf] = (wm * 128 + mf * 16 + l15) * 64 + lhi * 16;
#pragma unroll
  for (int nf = 0; nf < 2; ++nf) boff[nf] = (wn * 32 + nf * 16 + l15) * 64 + lhi * 16;

  bf16x8 a[4], rb1[2], rb3[2];
  f32x4 acc1[8][2], acc3[8][2];
#pragma unroll
  for (int i = 0; i < 8; ++i)
#pragma unroll
    for (int j = 0; j < 2; ++j) { acc1[i][j] = f32x4{0,0,0,0}; acc3[i][j] = f32x4{0,0,0,0}; }

#define LB(kt,kh) do { \
  rb1[0]=*(const bf16x8*)(ldsp+B1RG(kt,kh)+boff[0]); \
  rb1[1]=*(const bf16x8*)(ldsp+B1RG(kt,kh)+boff[1]); \
  rb3[0]=*(const bf16x8*)(ldsp+B3RG(kt,kh)+boff[0]); \
  rb3[1]=*(const bf16x8*)(ldsp+B3RG(kt,kh)+boff[1]); } while(0)
#define LA(kt,kh,mh) do { \
  a[0]=*(const bf16x8*)(ldsp+ARG(kt,kh)+aoff[(mh)*4+0]); \
  a[1]=*(const bf16x8*)(ldsp+ARG(kt,kh)+aoff[(mh)*4+1]); \
  a[2]=*(const bf16x8*)(ldsp+ARG(kt,kh)+aoff[(mh)*4+2]); \
  a[3]=*(const bf16x8*)(ldsp+ARG(kt,kh)+aoff[(mh)*4+3]); } while(0)
#define MM(mh) do { __builtin_amdgcn_s_setprio(1); \
  _Pragma("unroll") for (int mf = 0; mf < 4; ++mf) \
    _Pragma("unroll") for (int nf = 0; nf < 2; ++nf) { \
      acc1[(mh)*4+mf][nf] = MFMA16(a[mf], rb1[nf], acc1[(mh)*4+mf][nf]); \
      acc3[(mh)*4+mf][nf] = MFMA16(a[mf], rb3[nf], acc3[(mh)*4+mf][nf]); } \
  __builtin_amdgcn_s_setprio(0); } while(0)

  // prologue: kt0 fully, kt1 kh0
  SA(0,0); SA(0,1); SB(0,0); SB(0,1); SA(1,0); SB(1,0);
  VMC(4); BARX();

#pragma unroll 1
  for (int i = 0; i < 8; ++i) {
    const int k0 = 2*i, k1 = k0+1, k2 = k0+2, k3 = k0+3;
    const bool more = (i < 7);
    // ph0: (k0,kh0,mh0)
    LB(k0,0); LA(k0,0,0); SA(k1,1); SB(k1,1);
    BARX(); MM(0); BARX();
    // ph1: (k0,kh0,mh1)
    LA(k0,0,1);
    BARX(); MM(1); BARX();
    // ph2: (k0,kh1,mh0)
    LB(k0,1); LA(k0,1,0); if (more) SA(k2,0);
    BARX(); MM(0); BARX();
    // ph3: (k0,kh1,mh1)
    LA(k0,1,1); if (more) SB(k2,0);
    BARX(); MM(1); VMC(4); BARX();
    // ph4: (k1,kh0,mh0)
    LB(k1,0); LA(k1,0,0); if (more) { SA(k2,1); SB(k2,1); }
    BARX(); MM(0); BARX();
    // ph5: (k1,kh0,mh1)
    LA(k1,0,1);
    BARX(); MM(1); BARX();
    // ph6: (k1,kh1,mh0)
    LB(k1,1); LA(k1,1,0); if (more) SA(k3,0);
    BARX(); MM(0); BARX();
    // ph7: (k1,kh1,mh1)
    LA(k1,1,1); if (more) SB(k3,0);
    BARX(); MM(1); VMC(4); BARX();
  }

  // epilogue: silu(acc1)*acc3 -> bf16 h.  C/D map: row=lhi*4+q, col=l15.
  const int rb_ = wm * 128 + lhi * 4;
  const int cb_ = n0 + wn * 32 + l15;
#pragma unroll
  for (int mf = 0; mf < 8; ++mf)
#pragma unroll
    for (int q = 0; q < 4; ++q) {
      const int r = rb_ + mf * 16 + q;
      u16* hrow = hbuf + (hr0 + r) * H_;
#pragma unroll
      for (int nf = 0; nf < 2; ++nf) {
        const int c = cb_ + nf * 16;
        if (c < H_) {
          const float v1 = acc1[mf][nf][q], v3 = acc3[mf][nf][q];
          hrow[c] = f2bf((v1 / (1.f + __expf(-v1))) * v3);
        }
      }
    }
#undef ARG
#undef B1RG
#undef B3RG
#undef SA
#undef SB
#undef LB
#undef LA
#undef MM
}

// =====================================================================
// GEMM2 (4-phase x 16 MFMA): y[tok,:] (+)= w * (h[row,:] @ W2t)
// BM=256, BN=128, BK=64, 8 waves (2Mx4N), per-wave 128x32.
// K = 2752 -> 43 real K-tiles + 1 zero K-tile = 44 -> 22 iters.
// LDS: A 64KB + B 32KB = 96KB.
// =====================================================================
template<int MODE>   // 0: shared (plain store), 1: routed (atomicAdd * w)
__global__ __launch_bounds__(512, 2) void gemm2_8p(
    const u16* __restrict__ hbuf, const u16* __restrict__ w2t_all,
    float* __restrict__ y, const int* __restrict__ offsets,
    const int* __restrict__ ptok, const float* __restrict__ pw,
    const char* __restrict__ zp)
{
  __shared__ char lds[98304];
  const int t = threadIdx.x;
  const int bx = blockIdx.x;
  const int n0 = blockIdx.y * 128;

  int row0 = bx * 256; size_t hr0; const u16* bW;
  if (MODE == 1) {
    if (row0 >= offsets[8]) return;
    int e = 0;
#pragma unroll
    for (int i = 0; i < 7; ++i) if (row0 >= offsets[i + 1]) e = i + 1;
    bW = w2t_all + (size_t)e * (C_ * H_);
    hr0 = (size_t)row0;
  } else {
    bW = w2t_all;
    hr0 = (size_t)SHARED_HBASE + row0;
  }

  const int sr = t >> 2, sc = (t & 3) << 4;
  const char* aS0 = (const char*)hbuf + (hr0 + sr) * (size_t)(H_ * 2) + sc;
  const char* aS1 = (const char*)hbuf + (hr0 + 128 + sr) * (size_t)(H_ * 2) + sc;
  const char* bS  = (const char*)bW + (size_t)(n0 + sr) * (H_ * 2) + sc;
  const int wb = (t >> 6) << 10;
  char* ldsp = (char*)lds;
  const char* zpa = zp + t * 16;      // zero source, 8KB span
  const char* zpb = zp + t * 16;

#define A2RG(kt,kh) ((((kt)&1)*2+(kh))*16384)
#define B2RG(kt,kh) (65536 + ((((kt)&1)*2+(kh))*8192))
#define SA2(kt,kh) do { if ((kt) < 43) { const int go=(kt)*128+(kh)*64; \
    gld16(aS0+go, ldsp+A2RG(kt,kh)+wb); gld16(aS1+go, ldsp+A2RG(kt,kh)+8192+wb); } \
  else { gld16(zpa, ldsp+A2RG(kt,kh)+wb); gld16(zpa, ldsp+A2RG(kt,kh)+8192+wb); } } while(0)
#define SB2(kt,kh) do { if ((kt) < 43) { const int go=(kt)*128+(kh)*64; \
    gld16(bS+go, ldsp+B2RG(kt,kh)+wb); } \
  else { gld16(zpb, ldsp+B2RG(kt,kh)+wb); } } while(0)

  const int lane = t & 63, l15 = lane & 15, lhi = lane >> 4;
  const int wv = t >> 6, wm = wv >> 2, wn = wv & 3;
  int aoff[8], boff[2];
#pragma unroll
  for (int mf = 0; mf < 8; ++mf) aoff[mf] = (wm * 128 + mf * 16 + l15) * 64 + lhi * 16;
#pragma unroll
  for (int nf = 0; nf < 2; ++nf) boff[nf] = (wn * 32 + nf * 16 + l15) * 64 + lhi * 16;

  bf16x8 a8[8], rb[2];
  f32x4 acc[8][2];
#pragma unroll
  for (int i = 0; i < 8; ++i)
#pragma unroll
    for (int j = 0; j < 2; ++j) acc[i][j] = f32x4{0,0,0,0};

#define LB2(kt,kh) do { \
  rb[0]=*(const bf16x8*)(ldsp+B2RG(kt,kh)+boff[0]); \
  rb[1]=*(const bf16x8*)(ldsp+B2RG(kt,kh)+boff[1]); } while(0)
#define LA8(kt,kh) do { \
  _Pragma("unroll") for (int mf = 0; mf < 8; ++mf) \
    a8[mf]=*(const bf16x8*)(ldsp+A2RG(kt,kh)+aoff[mf]); } while(0)
#define MM2() do { __builtin_amdgcn_s_setprio(1); \
  _Pragma("unroll") for (int mf = 0; mf < 8; ++mf) \
    _Pragma("unroll") for (int nf = 0; nf < 2; ++nf) \
      acc[mf][nf] = MFMA16(a8[mf], rb[nf], acc[mf][nf]); \
  __builtin_amdgcn_s_setprio(0); } while(0)

  // prologue: kt0 fully, kt1 kh0
  SA2(0,0); SA2(0,1); SB2(0,0); SB2(0,1); SA2(1,0); SB2(1,0);
  VMC(3); BARX();

#pragma unroll 1
  for (int i = 0; i < 22; ++i) {
    const int k0 = 2*i, k1 = k0+1, k2 = k0+2, k3 = k0+3;
    const bool more = (i < 21);
    // P0: k0,kh0
    LB2(k0,0); LA8(k0,0); SA2(k1,1); SB2(k1,1);
    BARX(); MM2(); BARX();
    // P1: k0,kh1
    LB2(k0,1); LA8(k0,1); if (more) { SA2(k2,0); SB2(k2,0); }
    BARX(); MM2(); VMC(3); BARX();
    // P2: k1,kh0
    LB2(k1,0); LA8(k1,0); if (more) { SA2(k2,1); SB2(k2,1); }
    BARX(); MM2(); BARX();
    // P3: k1,kh1
    LB2(k1,1); LA8(k1,1); if (more) { SA2(k3,0); SB2(k3,0); }
    BARX(); MM2(); VMC(3); BARX();
  }

  // epilogue
  const int rb_ = wm * 128 + lhi * 4;
  const int cb_ = n0 + wn * 32 + l15;
#pragma unroll
  for (int mf = 0; mf < 8; ++mf)
#pragma unroll
    for (int q = 0; q < 4; ++q) {
      const int r = rb_ + mf * 16 + q;
      if (MODE == 0) {
        float* yr = y + (size_t)(row0 + r) * C_;
#pragma unroll
        for (int nf = 0; nf < 2; ++nf) yr[cb_ + nf * 16] = acc[mf][nf][q];
      } else {
        const float wgt = pw[row0 + r];
        if (wgt != 0.f) {
          const int tok = ptok[row0 + r];
          float* yr = y + (size_t)tok * C_;
#pragma unroll
          for (int nf = 0; nf < 2; ++nf)
            atomicAdd(yr + cb_ + nf * 16, wgt * acc[mf][nf][q]);
        }
      }
    }
#undef A2RG
#undef B2RG
#undef SA2
#undef SB2
#undef LB2
#undef LA8
#undef MM2
}

// ---------------- launch ----------------
extern "C" void kernel_launch(void* const* d_in, const int* in_sizes, int n_in,
                              void* d_out, int out_size, void* d_ws, size_t ws_size,
                              hipStream_t stream)
{
  const float* x    = (const float*)d_in[0];
  const float* gw   = (const float*)d_in[1];
  const float* bias = (const float*)d_in[2];
  const float* w1   = (const float*)d_in[3];
  const float* w2   = (const float*)d_in[4];
  const float* w3   = (const float*)d_in[5];
  const float* sw1  = (const float*)d_in[6];
  const float* sw2  = (const float*)d_in[7];
  const float* sw3  = (const float*)d_in[8];
  float* y = (float*)d_out;
  char* ws = (char*)d_ws;
  if (ws_size < WS_NEED) return;   // distinctive failure: output stays poisoned

  u16*   xb    = (u16*)(ws + OFF_XB);
  u16*   w1t   = (u16*)(ws + OFF_W1T);
  u16*   w3t   = (u16*)(ws + OFF_W3T);
  u16*   w2t   = (u16*)(ws + OFF_W2T);
  u16*   sw1t  = (u16*)(ws + OFF_SW1T);
  u16*   sw3t  = (u16*)(ws + OFF_SW3T);
  u16*   sw2t  = (u16*)(ws + OFF_SW2T);
  u16*   hbuf  = (u16*)(ws + OFF_H);
  char*  zp    = ws + OFF_ZP;
  int*   ridx  = (int*)(ws + OFF_RIDX);
  float* rwt   = (float*)(ws + OFF_RW);
  int*   offs  = (int*)(ws + OFF_OFFS);
  int*   ptok  = (int*)(ws + OFF_PTOK);
  float* pw    = (float*)(ws + OFF_PW);

  hipMemsetAsync(zp, 0, 16384, stream);
  gate_kernel<<<NTOK, 256, 0, stream>>>(x, gw, bias, xb, ridx, rwt);
  transpose_cs_kernel<<<dim3(H_ / 32, C_ / 32, 18), dim3(32, 8), 0, stream>>>(
      w1, w3, sw1, sw3, w1t, w3t, sw1t, sw3t);
  transpose_sc_kernel<<<dim3(C_ / 32, H_ / 32, 9), dim3(32, 8), 0, stream>>>(
      w2, sw2, w2t, sw2t);
  route_scan_kernel<<<1, 256, 0, stream>>>(ridx, rwt, offs, ptok, pw);

  // GEMM1: routed (bx<72) + shared (bx>=72) combined
  gemm1_8p<<<dim3(ROUTED_MB + SHARED_MB, 22), 512, 0, stream>>>(
      xb, w1t, w3t, sw1t, sw3t, hbuf, offs, ptok);
  // GEMM2: shared first (plain store initializes y), then routed atomics
  gemm2_8p<0><<<dim3(SHARED_MB, 8), 512, 0, stream>>>(
      hbuf, sw2t, y, offs, ptok, pw, zp);
  gemm2_8p<1><<<dim3(ROUTED_MB, 8), 512, 0, stream>>>(
      hbuf, w2t, y, offs, ptok, pw, zp);
}

// Round 3
// 757.378 us; speedup vs baseline: 1.0389x; 1.0389x over previous
//
#include <hip/hip_runtime.h>
#include <hip/hip_bf16.h>
#include <stdint.h>

// ---------------- problem constants ----------------
#define E_ 8
#define C_ 1024
#define H_ 2752
#define NTOK 8192            // B*T = 4*2048
#define CAP_ROWS 18432       // 16384 assignments + 8*256 pad, 256-aligned
#define ROUTED_MB 72         // CAP_ROWS/256
#define SHARED_MB 32         // NTOK/256
#define SHARED_HBASE 18432
#define HROWS 26624          // CAP_ROWS + NTOK

typedef unsigned short u16;
typedef __attribute__((ext_vector_type(8))) short bf16x8;   // 8 bf16 in 4 VGPRs
typedef __attribute__((ext_vector_type(4))) float f32x4;

// ---------------- ws layout (bytes) ----------------
static constexpr size_t SZ_XB    = (size_t)NTOK * C_ * 2;
static constexpr size_t SZ_WT    = (size_t)E_ * H_ * C_ * 2;
static constexpr size_t SZ_SWT   = (size_t)H_ * C_ * 2;
static constexpr size_t SZ_H     = (size_t)HROWS * H_ * 2;

static constexpr size_t OFF_XB   = 0;
static constexpr size_t OFF_W1T  = OFF_XB   + SZ_XB;
static constexpr size_t OFF_W3T  = OFF_W1T  + SZ_WT;
static constexpr size_t OFF_W2T  = OFF_W3T  + SZ_WT;
static constexpr size_t OFF_SW1T = OFF_W2T  + SZ_WT;
static constexpr size_t OFF_SW3T = OFF_SW1T + SZ_SWT;
static constexpr size_t OFF_SW2T = OFF_SW3T + SZ_SWT;
static constexpr size_t OFF_H    = OFF_SW2T + SZ_SWT;
static constexpr size_t OFF_ZP   = OFF_H    + SZ_H;                 // 16KB zero page
static constexpr size_t OFF_RIDX = OFF_ZP   + 16384;                // int[NTOK*2]
static constexpr size_t OFF_RW   = OFF_RIDX + (size_t)NTOK*2*4;     // float[NTOK*2]
static constexpr size_t OFF_OFFS = OFF_RW   + (size_t)NTOK*2*4;     // int[16]
static constexpr size_t OFF_PTOK = OFF_OFFS + 64;                   // int[CAP_ROWS]
static constexpr size_t OFF_PW   = OFF_PTOK + (size_t)CAP_ROWS*4;   // float[CAP_ROWS]
static constexpr size_t WS_NEED  = OFF_PW   + (size_t)CAP_ROWS*4;

// ---------------- helpers ----------------
__device__ __forceinline__ u16 f2bf(float f) {
  union { float f; uint32_t u; } v; v.f = f;
  uint32_t r = v.u + 0x7FFFu + ((v.u >> 16) & 1u);   // RNE
  return (u16)(r >> 16);
}

// async global->LDS, 16B per lane; LDS base wave-uniform, lane offset automatic.
__device__ __forceinline__ void gld16(const void* g, void* l) {
  uint32_t lo = (uint32_t)(uintptr_t)l;
  lo = __builtin_amdgcn_readfirstlane(lo);
  __builtin_amdgcn_global_load_lds(
      (const __attribute__((address_space(1))) void*)g,
      (__attribute__((address_space(3))) void*)(uintptr_t)lo, 16, 0, 0);
}

#define MFMA16(A,B,C) __builtin_amdgcn_mfma_f32_16x16x32_bf16((A),(B),(C),0,0,0)
#define BARX() do { asm volatile("" ::: "memory"); __builtin_amdgcn_s_barrier(); \
                    asm volatile("" ::: "memory"); } while (0)
#define VMC(N) asm volatile("s_waitcnt vmcnt(" #N ")" ::: "memory")

// ---------------- gating: fp32 scores, top-2, plus x->bf16 ----------------
__global__ __launch_bounds__(256) void gate_kernel(
    const float* __restrict__ x, const float* __restrict__ gw,
    const float* __restrict__ bias, u16* __restrict__ xb,
    int* __restrict__ ridx, float* __restrict__ rw)
{
  const int n = blockIdx.x, t = threadIdx.x;
  const float4 v = *(const float4*)(x + (size_t)n * C_ + t * 4);
  union { u16 u[4]; uint2 d; } pk;
  pk.u[0] = f2bf(v.x); pk.u[1] = f2bf(v.y); pk.u[2] = f2bf(v.z); pk.u[3] = f2bf(v.w);
  *(uint2*)(xb + (size_t)n * C_ + t * 4) = pk.d;

  float p[E_];
#pragma unroll
  for (int e = 0; e < E_; ++e) {
    const float4 g = *(const float4*)(gw + (size_t)e * C_ + t * 4);
    p[e] = v.x * g.x + v.y * g.y + v.z * g.z + v.w * g.w;
  }
#pragma unroll
  for (int e = 0; e < E_; ++e)
    for (int off = 32; off > 0; off >>= 1) p[e] += __shfl_down(p[e], off);

  __shared__ float red[4][E_];
  const int wv = t >> 6;
  if ((t & 63) == 0) {
#pragma unroll
    for (int e = 0; e < E_; ++e) red[wv][e] = p[e];
  }
  __syncthreads();
  if (t == 0) {
    float sc[E_], rt[E_];
#pragma unroll
    for (int e = 0; e < E_; ++e) {
      const float d = red[0][e] + red[1][e] + red[2][e] + red[3][e];
      const float s = 1.f / (1.f + expf(-d));
      sc[e] = s; rt[e] = s + bias[e];
    }
    int i0 = 0; float b0 = rt[0];
#pragma unroll
    for (int e = 1; e < E_; ++e) if (rt[e] > b0) { b0 = rt[e]; i0 = e; }
    int i1 = -1; float b1 = -1e30f;
#pragma unroll
    for (int e = 0; e < E_; ++e) if (e != i0 && rt[e] > b1) { b1 = rt[e]; i1 = e; }
    const float s0 = sc[i0], s1 = sc[i1];
    const float inv = 1.f / (s0 + s1 + 1e-8f);
    ridx[2 * n] = i0; ridx[2 * n + 1] = i1;
    rw[2 * n] = s0 * inv; rw[2 * n + 1] = s1 * inv;
  }
}

// ---------------- weight transpose + fp32->bf16 ----------------
__global__ __launch_bounds__(256) void transpose_cs_kernel(
    const float* __restrict__ w1, const float* __restrict__ w3,
    const float* __restrict__ sw1, const float* __restrict__ sw3,
    u16* __restrict__ w1t, u16* __restrict__ w3t,
    u16* __restrict__ sw1t, u16* __restrict__ sw3t)
{
  const int z = blockIdx.z;
  const float* src; u16* dst;
  if      (z < 8)  { src = w1 + (size_t)z * C_ * H_;       dst = w1t + (size_t)z * H_ * C_; }
  else if (z < 16) { src = w3 + (size_t)(z - 8) * C_ * H_; dst = w3t + (size_t)(z - 8) * H_ * C_; }
  else if (z == 16){ src = sw1; dst = sw1t; }
  else             { src = sw3; dst = sw3t; }
  __shared__ float tile[32][33];
  const int tx = threadIdx.x, ty = threadIdx.y;
  const int s0 = blockIdx.x * 32;   // H dim
  const int r0 = blockIdx.y * 32;   // C dim
#pragma unroll
  for (int i = 0; i < 4; ++i)
    tile[ty + 8 * i][tx] = src[(size_t)(r0 + ty + 8 * i) * H_ + s0 + tx];
  __syncthreads();
#pragma unroll
  for (int i = 0; i < 4; ++i)
    dst[(size_t)(s0 + ty + 8 * i) * C_ + r0 + tx] = f2bf(tile[tx][ty + 8 * i]);
}

__global__ __launch_bounds__(256) void transpose_sc_kernel(
    const float* __restrict__ w2, const float* __restrict__ sw2,
    u16* __restrict__ w2t, u16* __restrict__ sw2t)
{
  const int z = blockIdx.z;
  const float* src; u16* dst;
  if (z < 8) { src = w2 + (size_t)z * H_ * C_; dst = w2t + (size_t)z * C_ * H_; }
  else       { src = sw2; dst = sw2t; }
  __shared__ float tile[32][33];
  const int tx = threadIdx.x, ty = threadIdx.y;
  const int s0 = blockIdx.x * 32;   // C dim
  const int r0 = blockIdx.y * 32;   // H dim
#pragma unroll
  for (int i = 0; i < 4; ++i)
    tile[ty + 8 * i][tx] = src[(size_t)(r0 + ty + 8 * i) * C_ + s0 + tx];
  __syncthreads();
#pragma unroll
  for (int i = 0; i < 4; ++i)
    dst[(size_t)(s0 + ty + 8 * i) * H_ + r0 + tx] = f2bf(tile[tx][ty + 8 * i]);
}

// ---------------- deterministic routing scan/scatter (single block) ----------------
__global__ __launch_bounds__(256) void route_scan_kernel(
    const int* __restrict__ ridx, const float* __restrict__ rw,
    int* __restrict__ offsets, int* __restrict__ perm_tok, float* __restrict__ perm_w)
{
  __shared__ int cnt[256][E_];
  __shared__ int pref[E_][257];
  __shared__ int offs[E_ + 1];
  __shared__ int totals[E_];
  const int t = threadIdx.x;
#pragma unroll
  for (int e = 0; e < E_; ++e) cnt[t][e] = 0;
  for (int j = 0; j < 64; ++j) { const int e = ridx[t * 64 + j]; cnt[t][e]++; }
  __syncthreads();
  if (t < E_) {
    int run = 0;
    for (int i = 0; i < 256; ++i) { pref[t][i] = run; run += cnt[i][t]; }
    totals[t] = run; pref[t][256] = run;
  }
  __syncthreads();
  if (t == 0) {
    int o = 0;
    for (int e = 0; e < E_; ++e) { offs[e] = o; o += (totals[e] + 255) & ~255; }
    offs[E_] = o;
    for (int i = 0; i <= E_; ++i) offsets[i] = offs[i];
  }
  __syncthreads();
#pragma unroll
  for (int e = 0; e < E_; ++e) cnt[t][e] = offs[e] + pref[e][t];
  for (int j = 0; j < 64; ++j) {
    const int a = t * 64 + j;
    const int e = ridx[a];
    const int p = cnt[t][e]++;
    perm_tok[p] = a >> 1;
    perm_w[p] = rw[a];
  }
  __syncthreads();
  for (int e = 0; e < E_; ++e) {
    for (int p = offs[e] + totals[e] + t; p < offs[e + 1]; p += 256) {
      perm_tok[p] = 0; perm_w[p] = 0.f;     // pads: valid dummy row, zero weight
    }
  }
}

// =====================================================================
// GEMM1 (8-phase): h[row,:] = silu(x@W1) * (x@W3)  -> bf16
// BM=256, BN=128, BK=64, 8 waves (2Mx4N).
// LDS regions are [rows][64B]; bank-conflict swizzle: LDS[r][c] holds
// global[r][c ^ ((r>>1)&3)]; reads use chunk = lhi ^ ((l15>>1)&3).
// =====================================================================
__global__ __launch_bounds__(512, 2) void gemm1_8p(
    const u16* __restrict__ xb, const u16* __restrict__ w1t_all,
    const u16* __restrict__ w3t_all, const u16* __restrict__ sw1t,
    const u16* __restrict__ sw3t, u16* __restrict__ hbuf,
    const int* __restrict__ offsets, const int* __restrict__ ptok)
{
  __shared__ char lds[131072];
  const int t = threadIdx.x;
  const int bx = blockIdx.x;
  const int n0 = blockIdx.y * 128;

  const u16 *b1w, *b3w; int row0; size_t hr0; int gather;
  if (bx < ROUTED_MB) {
    row0 = bx * 256;
    if (row0 >= offsets[8]) return;
    int e = 0;
#pragma unroll
    for (int i = 0; i < 7; ++i) if (row0 >= offsets[i + 1]) e = i + 1;
    b1w = w1t_all + (size_t)e * (H_ * C_);
    b3w = w3t_all + (size_t)e * (H_ * C_);
    hr0 = (size_t)row0; gather = 1;
  } else {
    row0 = (bx - ROUTED_MB) * 256;
    b1w = sw1t; b3w = sw3t; hr0 = (size_t)SHARED_HBASE + row0; gather = 0;
  }

  // staging: thread t writes LDS row sr=t>>2, chunk t&3 (linear dest).
  // Source chunk pre-swizzled: (t&3) ^ ((sr>>1)&3), sr>>1 = t>>3.
  const int sr = t >> 2;
  const int sc = (((t & 3) ^ ((t >> 3) & 3)) << 4);
  const int ta0 = gather ? ptok[row0 + sr]       : (row0 + sr);
  const int ta1 = gather ? ptok[row0 + 128 + sr] : (row0 + 128 + sr);
  const char* aS0 = (const char*)xb + (size_t)ta0 * 2048 + sc;
  const char* aS1 = (const char*)xb + (size_t)ta1 * 2048 + sc;
  int nb = n0 + sr; if (nb > H_ - 1) nb = H_ - 1;     // N tail clamp
  const char* b1S = (const char*)b1w + (size_t)nb * 2048 + sc;
  const char* b3S = (const char*)b3w + (size_t)nb * 2048 + sc;
  const int wb = (t >> 6) << 10;
  char* ldsp = (char*)lds;

#define ARG(kt,kh)  ((((kt)&1)*2+(kh))*16384)
#define B1RG(kt,kh) (65536 + ((((kt)&1)*2+(kh))*8192))
#define B3RG(kt,kh) (98304 + ((((kt)&1)*2+(kh))*8192))
#define SA(kt,kh) do { const int go=(kt)*128+(kh)*64; \
  gld16(aS0+go, ldsp+ARG(kt,kh)+wb); gld16(aS1+go, ldsp+ARG(kt,kh)+8192+wb); } while(0)
#define SB(kt,kh) do { const int go=(kt)*128+(kh)*64; \
  gld16(b1S+go, ldsp+B1RG(kt,kh)+wb); gld16(b3S+go, ldsp+B3RG(kt,kh)+wb); } while(0)

  const int lane = t & 63, l15 = lane & 15, lhi = lane >> 4;
  const int wv = t >> 6, wm = wv >> 2, wn = wv & 3;
  const int cswz = ((lhi ^ ((l15 >> 1) & 3)) << 4);   // swizzled chunk, lane-const
  int aoff[8], boff[2];
#pragma unroll
  for (int mf = 0; mf < 8; ++mf) aoff[mf] = (wm * 128 + mf * 16 + l15) * 64 + cswz;
#pragma unroll
  for (int nf = 0; nf < 2; ++nf) boff[nf] = (wn * 32 + nf * 16 + l15) * 64 + cswz;

  bf16x8 a[4], rb1[2], rb3[2];
  f32x4 acc1[8][2], acc3[8][2];
#pragma unroll
  for (int i = 0; i < 8; ++i)
#pragma unroll
    for (int j = 0; j < 2; ++j) { acc1[i][j] = f32x4{0,0,0,0}; acc3[i][j] = f32x4{0,0,0,0}; }

#define LB(kt,kh) do { \
  rb1[0]=*(const bf16x8*)(ldsp+B1RG(kt,kh)+boff[0]); \
  rb1[1]=*(const bf16x8*)(ldsp+B1RG(kt,kh)+boff[1]); \
  rb3[0]=*(const bf16x8*)(ldsp+B3RG(kt,kh)+boff[0]); \
  rb3[1]=*(const bf16x8*)(ldsp+B3RG(kt,kh)+boff[1]); } while(0)
#define LA(kt,kh,mh) do { \
  a[0]=*(const bf16x8*)(ldsp+ARG(kt,kh)+aoff[(mh)*4+0]); \
  a[1]=*(const bf16x8*)(ldsp+ARG(kt,kh)+aoff[(mh)*4+1]); \
  a[2]=*(const bf16x8*)(ldsp+ARG(kt,kh)+aoff[(mh)*4+2]); \
  a[3]=*(const bf16x8*)(ldsp+ARG(kt,kh)+aoff[(mh)*4+3]); } while(0)
#define MM(mh) do { __builtin_amdgcn_s_setprio(1); \
  _Pragma("unroll") for (int mf = 0; mf < 4; ++mf) \
    _Pragma("unroll") for (int nf = 0; nf < 2; ++nf) { \
      acc1[(mh)*4+mf][nf] = MFMA16(a[mf], rb1[nf], acc1[(mh)*4+mf][nf]); \
      acc3[(mh)*4+mf][nf] = MFMA16(a[mf], rb3[nf], acc3[(mh)*4+mf][nf]); } \
  __builtin_amdgcn_s_setprio(0); } while(0)

  // prologue: kt0 fully, kt1 kh0
  SA(0,0); SA(0,1); SB(0,0); SB(0,1); SA(1,0); SB(1,0);
  VMC(4); BARX();

#pragma unroll 1
  for (int i = 0; i < 8; ++i) {
    const int k0 = 2*i, k1 = k0+1, k2 = k0+2, k3 = k0+3;
    const bool more = (i < 7);
    // ph0: (k0,kh0,mh0)
    LB(k0,0); LA(k0,0,0); SA(k1,1); SB(k1,1);
    BARX(); MM(0); BARX();
    // ph1: (k0,kh0,mh1)
    LA(k0,0,1);
    BARX(); MM(1); BARX();
    // ph2: (k0,kh1,mh0)
    LB(k0,1); LA(k0,1,0); if (more) SA(k2,0);
    BARX(); MM(0); BARX();
    // ph3: (k0,kh1,mh1)  — last iter: drain (k1,1) fully, nothing else in flight
    LA(k0,1,1); if (more) SB(k2,0);
    BARX(); MM(1);
    if (more) { VMC(4); } else { VMC(0); }
    BARX();
    // ph4: (k1,kh0,mh0)
    LB(k1,0); LA(k1,0,0); if (more) { SA(k2,1); SB(k2,1); }
    BARX(); MM(0); BARX();
    // ph5: (k1,kh0,mh1)
    LA(k1,0,1);
    BARX(); MM(1); BARX();
    // ph6: (k1,kh1,mh0)
    LB(k1,1); LA(k1,1,0); if (more) SA(k3,0);
    BARX(); MM(0); BARX();
    // ph7: (k1,kh1,mh1)
    LA(k1,1,1); if (more) SB(k3,0);
    BARX(); MM(1);
    if (more) { VMC(4); }
    BARX();
  }

  // epilogue: silu(acc1)*acc3 -> bf16 h.  C/D map: row=lhi*4+q, col=l15.
  const int rb_ = wm * 128 + lhi * 4;
  const int cb_ = n0 + wn * 32 + l15;
#pragma unroll
  for (int mf = 0; mf < 8; ++mf)
#pragma unroll
    for (int q = 0; q < 4; ++q) {
      const int r = rb_ + mf * 16 + q;
      u16* hrow = hbuf + (hr0 + r) * H_;
#pragma unroll
      for (int nf = 0; nf < 2; ++nf) {
        const int c = cb_ + nf * 16;
        if (c < H_) {
          const float v1 = acc1[mf][nf][q], v3 = acc3[mf][nf][q];
          hrow[c] = f2bf((v1 / (1.f + __expf(-v1))) * v3);
        }
      }
    }
#undef ARG
#undef B1RG
#undef B3RG
#undef SA
#undef SB
#undef LB
#undef LA
#undef MM
}

// =====================================================================
// GEMM2 (4-phase x 16 MFMA): y[tok,:] (+)= w * (h[row,:] @ W2t)
// K = 2752 -> 43 real K-tiles + 1 zero K-tile = 44 -> 22 iters.
// Same LDS swizzle as GEMM1.
// =====================================================================
template<int MODE>   // 0: shared (plain store), 1: routed (atomicAdd * w)
__global__ __launch_bounds__(512, 2) void gemm2_8p(
    const u16* __restrict__ hbuf, const u16* __restrict__ w2t_all,
    float* __restrict__ y, const int* __restrict__ offsets,
    const int* __restrict__ ptok, const float* __restrict__ pw,
    const char* __restrict__ zp)
{
  __shared__ char lds[98304];
  const int t = threadIdx.x;
  const int bx = blockIdx.x;
  const int n0 = blockIdx.y * 128;

  int row0 = bx * 256; size_t hr0; const u16* bW;
  if (MODE == 1) {
    if (row0 >= offsets[8]) return;
    int e = 0;
#pragma unroll
    for (int i = 0; i < 7; ++i) if (row0 >= offsets[i + 1]) e = i + 1;
    bW = w2t_all + (size_t)e * (C_ * H_);
    hr0 = (size_t)row0;
  } else {
    bW = w2t_all;
    hr0 = (size_t)SHARED_HBASE + row0;
  }

  const int sr = t >> 2;
  const int sc = (((t & 3) ^ ((t >> 3) & 3)) << 4);
  const char* aS0 = (const char*)hbuf + (hr0 + sr) * (size_t)(H_ * 2) + sc;
  const char* aS1 = (const char*)hbuf + (hr0 + 128 + sr) * (size_t)(H_ * 2) + sc;
  const char* bS  = (const char*)bW + (size_t)(n0 + sr) * (H_ * 2) + sc;
  const int wb = (t >> 6) << 10;
  char* ldsp = (char*)lds;
  const char* zpa = zp + t * 16;      // zero source (zeros regardless of swizzle)

#define A2RG(kt,kh) ((((kt)&1)*2+(kh))*16384)
#define B2RG(kt,kh) (65536 + ((((kt)&1)*2+(kh))*8192))
#define SA2(kt,kh) do { if ((kt) < 43) { const int go=(kt)*128+(kh)*64; \
    gld16(aS0+go, ldsp+A2RG(kt,kh)+wb); gld16(aS1+go, ldsp+A2RG(kt,kh)+8192+wb); } \
  else { gld16(zpa, ldsp+A2RG(kt,kh)+wb); gld16(zpa, ldsp+A2RG(kt,kh)+8192+wb); } } while(0)
#define SB2(kt,kh) do { if ((kt) < 43) { const int go=(kt)*128+(kh)*64; \
    gld16(bS+go, ldsp+B2RG(kt,kh)+wb); } \
  else { gld16(zpa, ldsp+B2RG(kt,kh)+wb); } } while(0)

  const int lane = t & 63, l15 = lane & 15, lhi = lane >> 4;
  const int wv = t >> 6, wm = wv >> 2, wn = wv & 3;
  const int cswz = ((lhi ^ ((l15 >> 1) & 3)) << 4);
  int aoff[8], boff[2];
#pragma unroll
  for (int mf = 0; mf < 8; ++mf) aoff[mf] = (wm * 128 + mf * 16 + l15) * 64 + cswz;
#pragma unroll
  for (int nf = 0; nf < 2; ++nf) boff[nf] = (wn * 32 + nf * 16 + l15) * 64 + cswz;

  bf16x8 a8[8], rb[2];
  f32x4 acc[8][2];
#pragma unroll
  for (int i = 0; i < 8; ++i)
#pragma unroll
    for (int j = 0; j < 2; ++j) acc[i][j] = f32x4{0,0,0,0};

#define LB2(kt,kh) do { \
  rb[0]=*(const bf16x8*)(ldsp+B2RG(kt,kh)+boff[0]); \
  rb[1]=*(const bf16x8*)(ldsp+B2RG(kt,kh)+boff[1]); } while(0)
#define LA8(kt,kh) do { \
  _Pragma("unroll") for (int mf = 0; mf < 8; ++mf) \
    a8[mf]=*(const bf16x8*)(ldsp+A2RG(kt,kh)+aoff[mf]); } while(0)
#define MM2() do { __builtin_amdgcn_s_setprio(1); \
  _Pragma("unroll") for (int mf = 0; mf < 8; ++mf) \
    _Pragma("unroll") for (int nf = 0; nf < 2; ++nf) \
      acc[mf][nf] = MFMA16(a8[mf], rb[nf], acc[mf][nf]); \
  __builtin_amdgcn_s_setprio(0); } while(0)

  // prologue: kt0 fully, kt1 kh0
  SA2(0,0); SA2(0,1); SB2(0,0); SB2(0,1); SA2(1,0); SB2(1,0);
  VMC(3); BARX();

#pragma unroll 1
  for (int i = 0; i < 22; ++i) {
    const int k0 = 2*i, k1 = k0+1, k2 = k0+2, k3 = k0+3;
    const bool more = (i < 21);
    // P0: k0,kh0
    LB2(k0,0); LA8(k0,0); SA2(k1,1); SB2(k1,1);
    BARX(); MM2(); BARX();
    // P1: k0,kh1 — last iter: drain (k1,1) fully
    LB2(k0,1); LA8(k0,1); if (more) { SA2(k2,0); SB2(k2,0); }
    BARX(); MM2();
    if (more) { VMC(3); } else { VMC(0); }
    BARX();
    // P2: k1,kh0
    LB2(k1,0); LA8(k1,0); if (more) { SA2(k2,1); SB2(k2,1); }
    BARX(); MM2(); BARX();
    // P3: k1,kh1
    LB2(k1,1); LA8(k1,1); if (more) { SA2(k3,0); SB2(k3,0); }
    BARX(); MM2();
    if (more) { VMC(3); }
    BARX();
  }

  // epilogue
  const int rb_ = wm * 128 + lhi * 4;
  const int cb_ = n0 + wn * 32 + l15;
#pragma unroll
  for (int mf = 0; mf < 8; ++mf)
#pragma unroll
    for (int q = 0; q < 4; ++q) {
      const int r = rb_ + mf * 16 + q;
      if (MODE == 0) {
        float* yr = y + (size_t)(row0 + r) * C_;
#pragma unroll
        for (int nf = 0; nf < 2; ++nf) yr[cb_ + nf * 16] = acc[mf][nf][q];
      } else {
        const float wgt = pw[row0 + r];
        if (wgt != 0.f) {
          const int tok = ptok[row0 + r];
          float* yr = y + (size_t)tok * C_;
#pragma unroll
          for (int nf = 0; nf < 2; ++nf)
            atomicAdd(yr + cb_ + nf * 16, wgt * acc[mf][nf][q]);
        }
      }
    }
#undef A2RG
#undef B2RG
#undef SA2
#undef SB2
#undef LB2
#undef LA8
#undef MM2
}

// ---------------- launch ----------------
extern "C" void kernel_launch(void* const* d_in, const int* in_sizes, int n_in,
                              void* d_out, int out_size, void* d_ws, size_t ws_size,
                              hipStream_t stream)
{
  const float* x    = (const float*)d_in[0];
  const float* gw   = (const float*)d_in[1];
  const float* bias = (const float*)d_in[2];
  const float* w1   = (const float*)d_in[3];
  const float* w2   = (const float*)d_in[4];
  const float* w3   = (const float*)d_in[5];
  const float* sw1  = (const float*)d_in[6];
  const float* sw2  = (const float*)d_in[7];
  const float* sw3  = (const float*)d_in[8];
  float* y = (float*)d_out;
  char* ws = (char*)d_ws;
  if (ws_size < WS_NEED) return;   // distinctive failure: output stays poisoned

  u16*   xb    = (u16*)(ws + OFF_XB);
  u16*   w1t   = (u16*)(ws + OFF_W1T);
  u16*   w3t   = (u16*)(ws + OFF_W3T);
  u16*   w2t   = (u16*)(ws + OFF_W2T);
  u16*   sw1t  = (u16*)(ws + OFF_SW1T);
  u16*   sw3t  = (u16*)(ws + OFF_SW3T);
  u16*   sw2t  = (u16*)(ws + OFF_SW2T);
  u16*   hbuf  = (u16*)(ws + OFF_H);
  char*  zp    = ws + OFF_ZP;
  int*   ridx  = (int*)(ws + OFF_RIDX);
  float* rwt   = (float*)(ws + OFF_RW);
  int*   offs  = (int*)(ws + OFF_OFFS);
  int*   ptok  = (int*)(ws + OFF_PTOK);
  float* pw    = (float*)(ws + OFF_PW);

  hipMemsetAsync(zp, 0, 16384, stream);
  gate_kernel<<<NTOK, 256, 0, stream>>>(x, gw, bias, xb, ridx, rwt);
  transpose_cs_kernel<<<dim3(H_ / 32, C_ / 32, 18), dim3(32, 8), 0, stream>>>(
      w1, w3, sw1, sw3, w1t, w3t, sw1t, sw3t);
  transpose_sc_kernel<<<dim3(C_ / 32, H_ / 32, 9), dim3(32, 8), 0, stream>>>(
      w2, sw2, w2t, sw2t);
  route_scan_kernel<<<1, 256, 0, stream>>>(ridx, rwt, offs, ptok, pw);

  // GEMM1: routed (bx<72) + shared (bx>=72) combined
  gemm1_8p<<<dim3(ROUTED_MB + SHARED_MB, 22), 512, 0, stream>>>(
      xb, w1t, w3t, sw1t, sw3t, hbuf, offs, ptok);
  // GEMM2: shared first (plain store initializes y), then routed atomics
  gemm2_8p<0><<<dim3(SHARED_MB, 8), 512, 0, stream>>>(
      hbuf, sw2t, y, offs, ptok, pw, zp);
  gemm2_8p<1><<<dim3(ROUTED_MB, 8), 512, 0, stream>>>(
      hbuf, w2t, y, offs, ptok, pw, zp);
}